// Round 14
// baseline (79.767 us; speedup 1.0000x reference)
//
#include <hip/hip_runtime.h>

// ContextVector additive-attention (Bahdanau) — round 14.
// R13 established: dec k-split didn't move total => enc-prep branch is the
// prep cost (1 block/CU = 1 wave/SIMD, latency-serial W-load chain).
// R14: enc-prep re-gridded to 1024 blocks x 4 t-rows (row group from bid =>
// A loads stay block-uniform scalar-pipe; R12 lesson). ~6 blocks/CU mixed
// grid => 4-6 waves/SIMD to hide W-load latency. dec-prep + attn VERBATIM
// from R13 (proven, absmax 4.9e-4).

constexpr int B  = 8;
constexpr int TE = 512;   // T_enc
constexpr int DE = 256;   // D_enc
constexpr int TD = 256;   // T_dec
constexpr int DD = 512;   // D_dec

constexpr float LOG2E  = 1.4426950408889634f;
constexpr float K2     = 2.8853900817779268f;   // 2*log2(e): exp2(K2*z) = e^{2z}
constexpr float ACLAMP = 10.0f;                 // pair products can't overflow

typedef float f2 __attribute__((ext_vector_type(2)));

__device__ __forceinline__ float fexp2(float x){ return __builtin_amdgcn_exp2f(x); }
__device__ __forceinline__ float frcp (float x){ return __builtin_amdgcn_rcpf(x); }
__device__ __forceinline__ f2 pk_mul(f2 a, f2 b){ f2 d; asm("v_pk_mul_f32 %0, %1, %2":"=v"(d):"v"(a),"v"(b)); return d; }
__device__ __forceinline__ f2 pk_fma(f2 a, f2 b, f2 c){ f2 d; asm("v_pk_fma_f32 %0, %1, %2, %3":"=v"(d):"v"(a),"v"(b),"v"(c)); return d; }

__device__ __forceinline__ float e2z(float z){   // e^{2z}, clamped
  return fexp2(K2 * fminf(fmaxf(z, -ACLAMP), ACLAMP));
}

// Prep: bid<1024: encE[b][e][t] = e^{2*(enc@Wenc)} transposed, 4 t-rows/block.
//       bid in [1024,1536): dec partial dots (R13 verbatim), block = (row-
//       group of 8, k-half): decP[row][kh*256+e].
// All A addresses block-uniform -> scalar pipe; W loads lane-coalesced.
__global__ __launch_bounds__(256)
void prep_kernel(const float* __restrict__ enc, const float* __restrict__ Wenc,
                 const float* __restrict__ dec, const float* __restrict__ Wdec,
                 float* __restrict__ encE, float* __restrict__ decP)
{
  __shared__ __align__(16) float LT[4][260];
  const int tid = threadIdx.x;
  const int bid = blockIdx.x;
  if (bid < 1024){
    const int r0 = bid*4;                  // global row = b*TE + t
    const int b = r0 >> 9, t0 = r0 & (TE-1);
    const int col = tid;
    float acc[4];
    #pragma unroll
    for (int r=0;r<4;r++) acc[r]=0.f;
    const float* Arow = enc + (size_t)r0*DE;     // block-uniform
    const float* wp   = Wenc + col;
    #pragma unroll 2
    for (int k4=0;k4<DE/4;k4++){
      const float w0 = wp[(size_t)(4*k4  )*DE];  // coalesced over lanes
      const float w1 = wp[(size_t)(4*k4+1)*DE];
      const float w2 = wp[(size_t)(4*k4+2)*DE];
      const float w3 = wp[(size_t)(4*k4+3)*DE];
      #pragma unroll
      for (int r=0;r<4;r++){
        const float4 av = *(const float4*)(Arow + (size_t)r*DE + 4*k4); // uniform
        acc[r] += av.x*w0 + av.y*w1 + av.z*w2 + av.w*w3;
      }
    }
    #pragma unroll
    for (int r=0;r<4;r++) LT[r][col] = e2z(acc[r]);
    __syncthreads();
    // store: thread e writes its 4 consecutive t as one float4
    float4 val;
    val.x = LT[0][col]; val.y = LT[1][col];
    val.z = LT[2][col]; val.w = LT[3][col];
    *(float4*)(encE + (size_t)(b*DE + col)*TE + t0) = val;
  } else {
    const int bid2 = bid - 1024;
    const int rg = bid2 >> 1;              // 256 row-groups of 8 rows
    const int kh = bid2 & 1;               // k-half
    const int r0 = rg*8;                   // global row = b*TD + s
    const int col = tid;
    float acc[8];
    #pragma unroll
    for (int r=0;r<8;r++) acc[r]=0.f;
    const float* Arow = dec + (size_t)r0*DD + kh*256;        // block-uniform
    const float* wp   = Wdec + (size_t)kh*256*DE + col;
    for (int k4=0;k4<64;k4++){
      const float w0 = wp[(size_t)(4*k4  )*DE];
      const float w1 = wp[(size_t)(4*k4+1)*DE];
      const float w2 = wp[(size_t)(4*k4+2)*DE];
      const float w3 = wp[(size_t)(4*k4+3)*DE];
      #pragma unroll
      for (int r=0;r<8;r++){
        const float4 av = *(const float4*)(Arow + (size_t)r*DD + 4*k4); // uniform
        acc[r] += av.x*w0 + av.y*w1 + av.z*w2 + av.w*w3;
      }
    }
    #pragma unroll
    for (int r=0;r<8;r++)
      decP[(size_t)(r0+r)*512 + kh*256 + col] = acc[r];      // coalesced
  }
}

// Main (R13 VERBATIM): block = (b, 4 decoder steps). 512 blocks x 1024 threads.
// Staging reads decP (raw partial dots, lives in outW) and applies e2z here.
// phase1: logit'[s][t] = sum_e vn_e * rcp(1 + Ea[e][t]*Eb[s][e])   (log2 domain)
// phase2: weights = 2^logit' / sum; overwrites this block's outW rows
// phase3: context = weights @ enc
__global__ __launch_bounds__(1024, 8)
void attn_kernel(const float* __restrict__ enc,
                 const float* __restrict__ v,
                 const float* __restrict__ encE, const float* __restrict__ decP,
                 float* __restrict__ outCtx, float* __restrict__ outW)
{
  __shared__ __align__(16) float ebp[DE*4*2];   // 8 KB {Eb,Eb} pairs per (e,s)
  __shared__ __align__(16) float vnp[DE*2];     // 2 KB {vn,vn} pairs
  __shared__ __align__(16) float part[16*TE];   // 32 KB [g*4+s][t]; multi-use
  __shared__ float wsum[16], rs[4];

  const int tid = threadIdx.x;
  const int bid = ((blockIdx.x & 7) << 6) | (blockIdx.x >> 3);  // XCD-bijective
  const int b  = bid >> 6;
  const int s0 = (bid & 63)*4;

  {
    if (tid < DE){
      // decP row (b*TD+s) = 512 floats: [kh=0: e 0..255][kh=1: e 0..255]
      const float* dp = decP + (size_t)(b*TD + s0)*512 + tid;
      const float g0 = e2z(dp[0]    + dp[256]);
      const float g1 = e2z(dp[512]  + dp[768]);
      const float g2 = e2z(dp[1024] + dp[1280]);
      const float g3 = e2z(dp[1536] + dp[1792]);
      float4 q0; q0.x=g0; q0.y=g0; q0.z=g1; q0.w=g1;
      float4 q1; q1.x=g2; q1.y=g2; q1.z=g3; q1.w=g3;
      *(float4*)&ebp[tid*8]   = q0;
      *(float4*)&ebp[tid*8+4] = q1;
      const float vnv = -2.f*LOG2E*v[tid];
      *(f2*)&vnp[tid*2] = f2{vnv, vnv};
    }
    __syncthreads();
  }

  // ---- phase 1: thread (g = e-quarter, q = t-pair). 64 e x 4 s x 2 t ----
  // Pairwise-batched reciprocal (overflow-proof with ACLAMP=10):
  //   R01 = rcp(d0*d1); 1/d0 = R01*d1; 1/d1 = R01*d0; same for (d2,d3).
  {
    const int g = tid >> 8, q = tid & 255;
    f2 acc0 = f2{0.f,0.f}, acc1 = f2{0.f,0.f}, acc2 = f2{0.f,0.f}, acc3 = f2{0.f,0.f};
    const f2 one2 = {1.f, 1.f};
    const float* xp = encE + (size_t)(b*DE + 64*g)*TE + 2*q;
    const float* ep = ebp + 64*g*8;
    const float* np = vnp + 64*g*2;
    #pragma unroll 2
    for (int i=0;i<64;i++){
      const f2 ea = *(const f2*)(xp + (size_t)i*TE);     // coalesced b64
      const float4 e01 = *(const float4*)(ep + i*8);     // uniform b128 {s0s0 s1s1}
      const float4 e23 = *(const float4*)(ep + i*8 + 4); // uniform b128 {s2s2 s3s3}
      const f2 vn2 = *(const f2*)(np + i*2);             // uniform b64
      const f2 d0 = pk_fma(ea, f2{e01.x, e01.y}, one2);
      const f2 d1 = pk_fma(ea, f2{e01.z, e01.w}, one2);
      const f2 d2 = pk_fma(ea, f2{e23.x, e23.y}, one2);
      const f2 d3 = pk_fma(ea, f2{e23.z, e23.w}, one2);
      const f2 D01 = pk_mul(d0, d1);                     // < 2^115.6 always
      const f2 D23 = pk_mul(d2, d3);
      const f2 R01 = {frcp(D01.x), frcp(D01.y)};
      const f2 R23 = {frcp(D23.x), frcp(D23.y)};
      acc0 = pk_fma(vn2, pk_mul(R01, d1), acc0);
      acc1 = pk_fma(vn2, pk_mul(R01, d0), acc1);
      acc2 = pk_fma(vn2, pk_mul(R23, d3), acc2);
      acc3 = pk_fma(vn2, pk_mul(R23, d2), acc3);
    }
    *(f2*)&part[(g*4 + 0)*TE + 2*q] = acc0;
    *(f2*)&part[(g*4 + 1)*TE + 2*q] = acc1;
    *(f2*)&part[(g*4 + 2)*TE + 2*q] = acc2;
    *(f2*)&part[(g*4 + 3)*TE + 2*q] = acc3;
  }
  __syncthreads();

  // ---- phase 2: wave w: s = w>>2, chunk c = w&3 (128 t). no max-subtract ----
  {
    const int w = tid >> 6, lane = tid & 63;
    const int s = w >> 2, c = w & 3;
    const int t0 = c*128 + 2*lane;
    f2 a = f2{0.f,0.f};
    #pragma unroll
    for (int g=0; g<4; g++){
      const f2 p = *(const f2*)&part[(g*4 + s)*TE + t0];
      a.x += p.x; a.y += p.y;
    }
    f2 ex; ex.x = fexp2(a.x); ex.y = fexp2(a.y);
    *(f2*)&part[(0*4 + s)*TE + t0] = ex;       // own slot (read above first)
    float sum = ex.x + ex.y;
    #pragma unroll
    for (int off=32; off>=1; off>>=1) sum += __shfl_xor(sum, off);
    if (lane==0) wsum[w] = sum;
    __syncthreads();
    const float S = wsum[s*4] + wsum[s*4+1] + wsum[s*4+2] + wsum[s*4+3];
    const float r = 1.0f / S;
    f2 wo; wo.x = ex.x*r; wo.y = ex.y*r;
    *(f2*)(outW + (size_t)(b*TD + s0 + s)*TE + t0) = wo;
    if (lane==0 && c==0) rs[s] = r;
  }
  // (no barrier needed: ex rows 0-3 published before the wsum barrier; ctx
  // partials go to rows 8-15, all phase-2 reads consumed before that barrier)

  // ---- phase 3: context. thread (h = t-quarter, e). 128 t x 4 s ----
  {
    const int h = tid >> 8, e = tid & 255;
    float c0=0.f, c1=0.f, c2=0.f, c3=0.f;
    const float* encB = enc + (size_t)(b*TE + 128*h)*DE + e;
    const int tb = 128*h;
    #pragma unroll 2
    for (int t4=0;t4<32;t4++){
      const float4 q0 = *(const float4*)&part[0*TE + tb + 4*t4];   // uniform b128
      const float4 q1 = *(const float4*)&part[1*TE + tb + 4*t4];
      const float4 q2 = *(const float4*)&part[2*TE + tb + 4*t4];
      const float4 q3 = *(const float4*)&part[3*TE + tb + 4*t4];
      const float f0 = encB[(size_t)(4*t4  )*DE];                  // coalesced
      const float f1 = encB[(size_t)(4*t4+1)*DE];
      const float f2_ = encB[(size_t)(4*t4+2)*DE];
      const float f3 = encB[(size_t)(4*t4+3)*DE];
      c0 += q0.x*f0+q0.y*f1+q0.z*f2_+q0.w*f3;
      c1 += q1.x*f0+q1.y*f1+q1.z*f2_+q1.w*f3;
      c2 += q2.x*f0+q2.y*f1+q2.z*f2_+q2.w*f3;
      c3 += q3.x*f0+q3.y*f1+q3.z*f2_+q3.w*f3;
    }
    float* partc = part + 8*TE;    // rows 8-15: [h*4+s][e]
    partc[(h*4+0)*DE + e] = c0;
    partc[(h*4+1)*DE + e] = c1;
    partc[(h*4+2)*DE + e] = c2;
    partc[(h*4+3)*DE + e] = c3;
  }
  __syncthreads();
  if (tid < DE){
    const float* partc = part + 8*TE;
    #pragma unroll
    for (int s=0;s<4;s++){
      const float val = (partc[(0*4+s)*DE + tid] + partc[(1*4+s)*DE + tid]
                       + partc[(2*4+s)*DE + tid] + partc[(3*4+s)*DE + tid]) * rs[s];
      outCtx[(size_t)(b*TD + s0 + s)*DE + tid] = val;
    }
  }
}

extern "C" void kernel_launch(void* const* d_in, const int* in_sizes, int n_in,
                              void* d_out, int out_size, void* d_ws, size_t ws_size,
                              hipStream_t stream)
{
  const float* enc  = (const float*)d_in[0];
  const float* dec  = (const float*)d_in[1];
  const float* Wenc = (const float*)d_in[2];
  const float* Wdec = (const float*)d_in[3];
  const float* v    = (const float*)d_in[4];
  float* outCtx = (float*)d_out;                       // (8,256,256)
  float* outW   = outCtx + (size_t)B*TD*DE;            // (8,256,512) = 4 MB
  float* encE   = (float*)d_ws;                        // 4 MB
  float* decP   = outW;                                // dec partial dots live
                                                       // in outW until attn
                                                       // overwrites with weights

  hipLaunchKernelGGL(prep_kernel, dim3(1536), dim3(256), 0, stream,
                     enc, Wenc, dec, Wdec, encE, decP);
  hipLaunchKernelGGL(attn_kernel, dim3(512), dim3(1024), 0, stream,
                     enc, v, encE, decP, outCtx, outW);
}

// Round 15
// 73.594 us; speedup vs baseline: 1.0839x; 1.0839x over previous
//
#include <hip/hip_runtime.h>

// ContextVector additive-attention (Bahdanau) — round 15.
// R14 lesson: more/thinner prep blocks = worse (W traffic per block is fixed;
// load:FMA ratio degrades). R12 lesson root-caused: LLVM divergence analysis
// can't see tid>>8 is wave-uniform -> demotes A loads to VMEM. Fix:
// __builtin_amdgcn_readfirstlane forces SGPR -> scalar-pipe A loads survive
// an in-block k-split. R15 prep: 256 enc blocks + 256 dec blocks x 512 thr,
// kh = readfirstlane(tid>>8) halves each dependent-load chain and doubles
// waves/SIMD. attn: R13 VERBATIM (51us, absmax 4.9e-4, proven).

constexpr int B  = 8;
constexpr int TE = 512;   // T_enc
constexpr int DE = 256;   // D_enc
constexpr int TD = 256;   // T_dec
constexpr int DD = 512;   // D_dec

constexpr float LOG2E  = 1.4426950408889634f;
constexpr float K2     = 2.8853900817779268f;   // 2*log2(e): exp2(K2*z) = e^{2z}
constexpr float ACLAMP = 10.0f;                 // pair products can't overflow

typedef float f2 __attribute__((ext_vector_type(2)));

__device__ __forceinline__ float fexp2(float x){ return __builtin_amdgcn_exp2f(x); }
__device__ __forceinline__ float frcp (float x){ return __builtin_amdgcn_rcpf(x); }
__device__ __forceinline__ f2 pk_mul(f2 a, f2 b){ f2 d; asm("v_pk_mul_f32 %0, %1, %2":"=v"(d):"v"(a),"v"(b)); return d; }
__device__ __forceinline__ f2 pk_fma(f2 a, f2 b, f2 c){ f2 d; asm("v_pk_fma_f32 %0, %1, %2, %3":"=v"(d):"v"(a),"v"(b),"v"(c)); return d; }

__device__ __forceinline__ float e2z(float z){   // e^{2z}, clamped
  return fexp2(K2 * fminf(fmaxf(z, -ACLAMP), ACLAMP));
}

// Prep: 512 blocks x 512 threads.
//  bid<256 : encE[b][e][t] = e^{2*(enc@Wenc)} transposed, 16 t-rows/block.
//            kh = readfirstlane(tid>>8) splits k into halves (32 iters each);
//            partials meet in LDS, tid<256 reduces + e2z, R8 transpose-store.
//  bid>=256: decP[row][kh*256+e] partial dots, 8 s-rows/block, kh in-block.
// All A addresses wave-uniform (bid/const/SGPR only) -> scalar pipe.
__global__ __launch_bounds__(512)
void prep_kernel(const float* __restrict__ enc, const float* __restrict__ Wenc,
                 const float* __restrict__ dec, const float* __restrict__ Wdec,
                 float* __restrict__ encE, float* __restrict__ decP)
{
  __shared__ __align__(16) float LT[2][16][257];   // 32.9 KB
  const int tid = threadIdx.x;
  const int bid = blockIdx.x;
  const int kh  = __builtin_amdgcn_readfirstlane(tid >> 8);  // wave-uniform 0/1
  const int col = tid & 255;
  if (bid < 256){
    const int r0 = bid*16;                 // global row = b*TE + t
    const int b = r0 >> 9, t0 = r0 & (TE-1);
    float acc[16];
    #pragma unroll
    for (int r=0;r<16;r++) acc[r]=0.f;
    const float* Arow = enc + (size_t)r0*DE + kh*128;        // SGPR-uniform
    const float* wp   = Wenc + (size_t)kh*128*DE + col;
    for (int k4=0;k4<32;k4++){
      const float w0 = wp[(size_t)(4*k4  )*DE];   // coalesced over lanes
      const float w1 = wp[(size_t)(4*k4+1)*DE];
      const float w2 = wp[(size_t)(4*k4+2)*DE];
      const float w3 = wp[(size_t)(4*k4+3)*DE];
      #pragma unroll
      for (int r=0;r<16;r++){
        const float4 av = *(const float4*)(Arow + (size_t)r*DE + 4*k4); // uniform
        acc[r] += av.x*w0 + av.y*w1 + av.z*w2 + av.w*w3;
      }
    }
    #pragma unroll
    for (int r=0;r<16;r++) LT[kh][r][col] = acc[r];
    __syncthreads();
    if (tid < 256){
      #pragma unroll
      for (int r=0;r<16;r++)
        LT[0][r][col] = e2z(LT[0][r][col] + LT[1][r][col]);
    }
    __syncthreads();
    if (tid < 256){
      // store: wave writes 16 e-rows x 16 t = full 64B lines (R8 verbatim)
      const int wv = tid>>6, lane = tid&63, le = lane>>2, jj = lane&3;
      #pragma unroll
      for (int p=0;p<4;p++){
        const int e = p*64 + wv*16 + le;
        float4 val;
        val.x = LT[0][4*jj+0][e]; val.y = LT[0][4*jj+1][e];
        val.z = LT[0][4*jj+2][e]; val.w = LT[0][4*jj+3][e];
        *(float4*)(encE + (size_t)(b*DE + e)*TE + t0 + 4*jj) = val;
      }
    }
  } else {
    const int rg = bid - 256;              // 256 row-groups of 8 rows
    const int r0 = rg*8;                   // global row = b*TD + s
    float acc[8];
    #pragma unroll
    for (int r=0;r<8;r++) acc[r]=0.f;
    const float* Arow = dec + (size_t)r0*DD + kh*256;        // SGPR-uniform
    const float* wp   = Wdec + (size_t)kh*256*DE + col;
    for (int k4=0;k4<64;k4++){
      const float w0 = wp[(size_t)(4*k4  )*DE];
      const float w1 = wp[(size_t)(4*k4+1)*DE];
      const float w2 = wp[(size_t)(4*k4+2)*DE];
      const float w3 = wp[(size_t)(4*k4+3)*DE];
      #pragma unroll
      for (int r=0;r<8;r++){
        const float4 av = *(const float4*)(Arow + (size_t)r*DD + 4*k4); // uniform
        acc[r] += av.x*w0 + av.y*w1 + av.z*w2 + av.w*w3;
      }
    }
    #pragma unroll
    for (int r=0;r<8;r++)
      decP[(size_t)(r0+r)*512 + kh*256 + col] = acc[r];      // coalesced
  }
}

// Main (R13 VERBATIM): block = (b, 4 decoder steps). 512 blocks x 1024 threads.
// Staging reads decP (raw partial dots, lives in outW) and applies e2z here.
// phase1: logit'[s][t] = sum_e vn_e * rcp(1 + Ea[e][t]*Eb[s][e])   (log2 domain)
// phase2: weights = 2^logit' / sum; overwrites this block's outW rows
// phase3: context = weights @ enc
__global__ __launch_bounds__(1024, 8)
void attn_kernel(const float* __restrict__ enc,
                 const float* __restrict__ v,
                 const float* __restrict__ encE, const float* __restrict__ decP,
                 float* __restrict__ outCtx, float* __restrict__ outW)
{
  __shared__ __align__(16) float ebp[DE*4*2];   // 8 KB {Eb,Eb} pairs per (e,s)
  __shared__ __align__(16) float vnp[DE*2];     // 2 KB {vn,vn} pairs
  __shared__ __align__(16) float part[16*TE];   // 32 KB [g*4+s][t]; multi-use
  __shared__ float wsum[16], rs[4];

  const int tid = threadIdx.x;
  const int bid = ((blockIdx.x & 7) << 6) | (blockIdx.x >> 3);  // XCD-bijective
  const int b  = bid >> 6;
  const int s0 = (bid & 63)*4;

  {
    if (tid < DE){
      // decP row (b*TD+s) = 512 floats: [kh=0: e 0..255][kh=1: e 0..255]
      const float* dp = decP + (size_t)(b*TD + s0)*512 + tid;
      const float g0 = e2z(dp[0]    + dp[256]);
      const float g1 = e2z(dp[512]  + dp[768]);
      const float g2 = e2z(dp[1024] + dp[1280]);
      const float g3 = e2z(dp[1536] + dp[1792]);
      float4 q0; q0.x=g0; q0.y=g0; q0.z=g1; q0.w=g1;
      float4 q1; q1.x=g2; q1.y=g2; q1.z=g3; q1.w=g3;
      *(float4*)&ebp[tid*8]   = q0;
      *(float4*)&ebp[tid*8+4] = q1;
      const float vnv = -2.f*LOG2E*v[tid];
      *(f2*)&vnp[tid*2] = f2{vnv, vnv};
    }
    __syncthreads();
  }

  // ---- phase 1: thread (g = e-quarter, q = t-pair). 64 e x 4 s x 2 t ----
  // Pairwise-batched reciprocal (overflow-proof with ACLAMP=10):
  //   R01 = rcp(d0*d1); 1/d0 = R01*d1; 1/d1 = R01*d0; same for (d2,d3).
  {
    const int g = tid >> 8, q = tid & 255;
    f2 acc0 = f2{0.f,0.f}, acc1 = f2{0.f,0.f}, acc2 = f2{0.f,0.f}, acc3 = f2{0.f,0.f};
    const f2 one2 = {1.f, 1.f};
    const float* xp = encE + (size_t)(b*DE + 64*g)*TE + 2*q;
    const float* ep = ebp + 64*g*8;
    const float* np = vnp + 64*g*2;
    #pragma unroll 2
    for (int i=0;i<64;i++){
      const f2 ea = *(const f2*)(xp + (size_t)i*TE);     // coalesced b64
      const float4 e01 = *(const float4*)(ep + i*8);     // uniform b128 {s0s0 s1s1}
      const float4 e23 = *(const float4*)(ep + i*8 + 4); // uniform b128 {s2s2 s3s3}
      const f2 vn2 = *(const f2*)(np + i*2);             // uniform b64
      const f2 d0 = pk_fma(ea, f2{e01.x, e01.y}, one2);
      const f2 d1 = pk_fma(ea, f2{e01.z, e01.w}, one2);
      const f2 d2 = pk_fma(ea, f2{e23.x, e23.y}, one2);
      const f2 d3 = pk_fma(ea, f2{e23.z, e23.w}, one2);
      const f2 D01 = pk_mul(d0, d1);                     // < 2^115.6 always
      const f2 D23 = pk_mul(d2, d3);
      const f2 R01 = {frcp(D01.x), frcp(D01.y)};
      const f2 R23 = {frcp(D23.x), frcp(D23.y)};
      acc0 = pk_fma(vn2, pk_mul(R01, d1), acc0);
      acc1 = pk_fma(vn2, pk_mul(R01, d0), acc1);
      acc2 = pk_fma(vn2, pk_mul(R23, d3), acc2);
      acc3 = pk_fma(vn2, pk_mul(R23, d2), acc3);
    }
    *(f2*)&part[(g*4 + 0)*TE + 2*q] = acc0;
    *(f2*)&part[(g*4 + 1)*TE + 2*q] = acc1;
    *(f2*)&part[(g*4 + 2)*TE + 2*q] = acc2;
    *(f2*)&part[(g*4 + 3)*TE + 2*q] = acc3;
  }
  __syncthreads();

  // ---- phase 2: wave w: s = w>>2, chunk c = w&3 (128 t). no max-subtract ----
  {
    const int w = tid >> 6, lane = tid & 63;
    const int s = w >> 2, c = w & 3;
    const int t0 = c*128 + 2*lane;
    f2 a = f2{0.f,0.f};
    #pragma unroll
    for (int g=0; g<4; g++){
      const f2 p = *(const f2*)&part[(g*4 + s)*TE + t0];
      a.x += p.x; a.y += p.y;
    }
    f2 ex; ex.x = fexp2(a.x); ex.y = fexp2(a.y);
    *(f2*)&part[(0*4 + s)*TE + t0] = ex;       // own slot (read above first)
    float sum = ex.x + ex.y;
    #pragma unroll
    for (int off=32; off>=1; off>>=1) sum += __shfl_xor(sum, off);
    if (lane==0) wsum[w] = sum;
    __syncthreads();
    const float S = wsum[s*4] + wsum[s*4+1] + wsum[s*4+2] + wsum[s*4+3];
    const float r = 1.0f / S;
    f2 wo; wo.x = ex.x*r; wo.y = ex.y*r;
    *(f2*)(outW + (size_t)(b*TD + s0 + s)*TE + t0) = wo;
    if (lane==0 && c==0) rs[s] = r;
  }
  // (no barrier needed: ex rows 0-3 published before the wsum barrier; ctx
  // partials go to rows 8-15, all phase-2 reads consumed before that barrier)

  // ---- phase 3: context. thread (h = t-quarter, e). 128 t x 4 s ----
  {
    const int h = tid >> 8, e = tid & 255;
    float c0=0.f, c1=0.f, c2=0.f, c3=0.f;
    const float* encB = enc + (size_t)(b*TE + 128*h)*DE + e;
    const int tb = 128*h;
    #pragma unroll 2
    for (int t4=0;t4<32;t4++){
      const float4 q0 = *(const float4*)&part[0*TE + tb + 4*t4];   // uniform b128
      const float4 q1 = *(const float4*)&part[1*TE + tb + 4*t4];
      const float4 q2 = *(const float4*)&part[2*TE + tb + 4*t4];
      const float4 q3 = *(const float4*)&part[3*TE + tb + 4*t4];
      const float f0 = encB[(size_t)(4*t4  )*DE];                  // coalesced
      const float f1 = encB[(size_t)(4*t4+1)*DE];
      const float f2_ = encB[(size_t)(4*t4+2)*DE];
      const float f3 = encB[(size_t)(4*t4+3)*DE];
      c0 += q0.x*f0+q0.y*f1+q0.z*f2_+q0.w*f3;
      c1 += q1.x*f0+q1.y*f1+q1.z*f2_+q1.w*f3;
      c2 += q2.x*f0+q2.y*f1+q2.z*f2_+q2.w*f3;
      c3 += q3.x*f0+q3.y*f1+q3.z*f2_+q3.w*f3;
    }
    float* partc = part + 8*TE;    // rows 8-15: [h*4+s][e]
    partc[(h*4+0)*DE + e] = c0;
    partc[(h*4+1)*DE + e] = c1;
    partc[(h*4+2)*DE + e] = c2;
    partc[(h*4+3)*DE + e] = c3;
  }
  __syncthreads();
  if (tid < DE){
    const float* partc = part + 8*TE;
    #pragma unroll
    for (int s=0;s<4;s++){
      const float val = (partc[(0*4+s)*DE + tid] + partc[(1*4+s)*DE + tid]
                       + partc[(2*4+s)*DE + tid] + partc[(3*4+s)*DE + tid]) * rs[s];
      outCtx[(size_t)(b*TD + s0 + s)*DE + tid] = val;
    }
  }
}

extern "C" void kernel_launch(void* const* d_in, const int* in_sizes, int n_in,
                              void* d_out, int out_size, void* d_ws, size_t ws_size,
                              hipStream_t stream)
{
  const float* enc  = (const float*)d_in[0];
  const float* dec  = (const float*)d_in[1];
  const float* Wenc = (const float*)d_in[2];
  const float* Wdec = (const float*)d_in[3];
  const float* v    = (const float*)d_in[4];
  float* outCtx = (float*)d_out;                       // (8,256,256)
  float* outW   = outCtx + (size_t)B*TD*DE;            // (8,256,512) = 4 MB
  float* encE   = (float*)d_ws;                        // 4 MB
  float* decP   = outW;                                // dec partial dots live
                                                       // in outW until attn
                                                       // overwrites with weights

  hipLaunchKernelGGL(prep_kernel, dim3(512), dim3(512), 0, stream,
                     enc, Wenc, dec, Wdec, encE, decP);
  hipLaunchKernelGGL(attn_kernel, dim3(512), dim3(1024), 0, stream,
                     enc, v, encE, decP, outCtx, outW);
}

// Round 16
// 73.206 us; speedup vs baseline: 1.0896x; 1.0053x over previous
//
#include <hip/hip_runtime.h>

// ContextVector additive-attention (Bahdanau) — round 16.
// R15 null localized prep's excess to remaining dependent-chain latency at
// low occupancy. R16 prep: 1024-thread blocks, 4-way readfirstlane k-split
// (enc chain 16 iters, dec 32), 32 waves/CU. All A addresses SGPR-uniform
// (R12 rule). attn: R13 VERBATIM (51.0us, proven 3x).
// Pre-commit: if total >= 71us, prep is declared non-latency-bound and the
// session floor (~73us) stands.

constexpr int B  = 8;
constexpr int TE = 512;   // T_enc
constexpr int DE = 256;   // D_enc
constexpr int TD = 256;   // T_dec
constexpr int DD = 512;   // D_dec

constexpr float LOG2E  = 1.4426950408889634f;
constexpr float K2     = 2.8853900817779268f;   // 2*log2(e): exp2(K2*z) = e^{2z}
constexpr float ACLAMP = 10.0f;                 // pair products can't overflow

typedef float f2 __attribute__((ext_vector_type(2)));

__device__ __forceinline__ float fexp2(float x){ return __builtin_amdgcn_exp2f(x); }
__device__ __forceinline__ float frcp (float x){ return __builtin_amdgcn_rcpf(x); }
__device__ __forceinline__ f2 pk_mul(f2 a, f2 b){ f2 d; asm("v_pk_mul_f32 %0, %1, %2":"=v"(d):"v"(a),"v"(b)); return d; }
__device__ __forceinline__ f2 pk_fma(f2 a, f2 b, f2 c){ f2 d; asm("v_pk_fma_f32 %0, %1, %2, %3":"=v"(d):"v"(a),"v"(b),"v"(c)); return d; }

__device__ __forceinline__ float e2z(float z){   // e^{2z}, clamped
  return fexp2(K2 * fminf(fmaxf(z, -ACLAMP), ACLAMP));
}

// Prep: 512 blocks x 1024 threads, kq = readfirstlane(tid>>8) in 0..3.
//  bid<256 : encE[b][e][t] = e^{2*(enc@Wenc)} transposed, 16 t-rows/block.
//            k split in quarters (16 iters); 3 partials via LDS; kq=0 reduces,
//            e2z, R8 transpose-store.
//  bid>=256: decP 8 s-rows/block; k in quarters (32 iters); kq 1/3 stash in
//            LDS, kq 0/2 reduce -> decP[row][(kq>>1)*256+e] (2-half layout,
//            attn staging unchanged).
__global__ __launch_bounds__(1024, 8)
void prep_kernel(const float* __restrict__ enc, const float* __restrict__ Wenc,
                 const float* __restrict__ dec, const float* __restrict__ Wdec,
                 float* __restrict__ encE, float* __restrict__ decP)
{
  __shared__ __align__(16) float LP[3][16][257];   // 49.3 KB
  const int tid = threadIdx.x;
  const int bid = blockIdx.x;
  const int kq  = __builtin_amdgcn_readfirstlane(tid >> 8);  // wave-uniform 0..3
  const int col = tid & 255;
  if (bid < 256){
    const int r0 = bid*16;                 // global row = b*TE + t
    const int b = r0 >> 9, t0 = r0 & (TE-1);
    float acc[16];
    #pragma unroll
    for (int r=0;r<16;r++) acc[r]=0.f;
    const float* Arow = enc + (size_t)r0*DE + kq*64;         // SGPR-uniform
    const float* wp   = Wenc + (size_t)kq*64*DE + col;
    for (int k4=0;k4<16;k4++){
      const float w0 = wp[(size_t)(4*k4  )*DE];   // coalesced over lanes
      const float w1 = wp[(size_t)(4*k4+1)*DE];
      const float w2 = wp[(size_t)(4*k4+2)*DE];
      const float w3 = wp[(size_t)(4*k4+3)*DE];
      #pragma unroll
      for (int r=0;r<16;r++){
        const float4 av = *(const float4*)(Arow + (size_t)r*DE + 4*k4); // uniform
        acc[r] += av.x*w0 + av.y*w1 + av.z*w2 + av.w*w3;
      }
    }
    if (kq > 0){
      #pragma unroll
      for (int r=0;r<16;r++) LP[kq-1][r][col] = acc[r];
    }
    __syncthreads();
    if (kq == 0){
      #pragma unroll
      for (int r=0;r<16;r++){
        const float s = ((acc[r] + LP[0][r][col]) + LP[1][r][col]) + LP[2][r][col];
        LP[0][r][col] = e2z(s);     // same-thread same-slot overwrite
      }
    }
    __syncthreads();
    if (kq == 0){
      // store: 4 waves write 256 e-rows x 16 t = full 64B lines (R8 pattern)
      const int wv = tid>>6, lane = tid&63, le = lane>>2, jj = lane&3;
      #pragma unroll
      for (int p=0;p<4;p++){
        const int e = p*64 + wv*16 + le;
        float4 val;
        val.x = LP[0][4*jj+0][e]; val.y = LP[0][4*jj+1][e];
        val.z = LP[0][4*jj+2][e]; val.w = LP[0][4*jj+3][e];
        *(float4*)(encE + (size_t)(b*DE + e)*TE + t0 + 4*jj) = val;
      }
    }
  } else {
    const int rg = bid - 256;              // 256 row-groups of 8 rows
    const int r0 = rg*8;                   // global row = b*TD + s
    float acc[8];
    #pragma unroll
    for (int r=0;r<8;r++) acc[r]=0.f;
    const float* Arow = dec + (size_t)r0*DD + kq*128;        // SGPR-uniform
    const float* wp   = Wdec + (size_t)kq*128*DE + col;
    for (int k4=0;k4<32;k4++){
      const float w0 = wp[(size_t)(4*k4  )*DE];
      const float w1 = wp[(size_t)(4*k4+1)*DE];
      const float w2 = wp[(size_t)(4*k4+2)*DE];
      const float w3 = wp[(size_t)(4*k4+3)*DE];
      #pragma unroll
      for (int r=0;r<8;r++){
        const float4 av = *(const float4*)(Arow + (size_t)r*DD + 4*k4); // uniform
        acc[r] += av.x*w0 + av.y*w1 + av.z*w2 + av.w*w3;
      }
    }
    if (kq & 1){
      #pragma unroll
      for (int r=0;r<8;r++) LP[0][(kq>>1)*8 + r][col] = acc[r];
    }
    __syncthreads();
    if (!(kq & 1)){
      const int h = kq >> 1;               // 0 or 1 -> decP half
      #pragma unroll
      for (int r=0;r<8;r++){
        const float s = acc[r] + LP[0][h*8 + r][col];
        decP[(size_t)(r0+r)*512 + h*256 + col] = s;          // coalesced
      }
    }
  }
}

// Main (R13 VERBATIM): block = (b, 4 decoder steps). 512 blocks x 1024 threads.
// Staging reads decP (raw partial dots, lives in outW) and applies e2z here.
// phase1: logit'[s][t] = sum_e vn_e * rcp(1 + Ea[e][t]*Eb[s][e])   (log2 domain)
// phase2: weights = 2^logit' / sum; overwrites this block's outW rows
// phase3: context = weights @ enc
__global__ __launch_bounds__(1024, 8)
void attn_kernel(const float* __restrict__ enc,
                 const float* __restrict__ v,
                 const float* __restrict__ encE, const float* __restrict__ decP,
                 float* __restrict__ outCtx, float* __restrict__ outW)
{
  __shared__ __align__(16) float ebp[DE*4*2];   // 8 KB {Eb,Eb} pairs per (e,s)
  __shared__ __align__(16) float vnp[DE*2];     // 2 KB {vn,vn} pairs
  __shared__ __align__(16) float part[16*TE];   // 32 KB [g*4+s][t]; multi-use
  __shared__ float wsum[16], rs[4];

  const int tid = threadIdx.x;
  const int bid = ((blockIdx.x & 7) << 6) | (blockIdx.x >> 3);  // XCD-bijective
  const int b  = bid >> 6;
  const int s0 = (bid & 63)*4;

  {
    if (tid < DE){
      // decP row (b*TD+s) = 512 floats: [kh=0: e 0..255][kh=1: e 0..255]
      const float* dp = decP + (size_t)(b*TD + s0)*512 + tid;
      const float g0 = e2z(dp[0]    + dp[256]);
      const float g1 = e2z(dp[512]  + dp[768]);
      const float g2 = e2z(dp[1024] + dp[1280]);
      const float g3 = e2z(dp[1536] + dp[1792]);
      float4 q0; q0.x=g0; q0.y=g0; q0.z=g1; q0.w=g1;
      float4 q1; q1.x=g2; q1.y=g2; q1.z=g3; q1.w=g3;
      *(float4*)&ebp[tid*8]   = q0;
      *(float4*)&ebp[tid*8+4] = q1;
      const float vnv = -2.f*LOG2E*v[tid];
      *(f2*)&vnp[tid*2] = f2{vnv, vnv};
    }
    __syncthreads();
  }

  // ---- phase 1: thread (g = e-quarter, q = t-pair). 64 e x 4 s x 2 t ----
  // Pairwise-batched reciprocal (overflow-proof with ACLAMP=10):
  //   R01 = rcp(d0*d1); 1/d0 = R01*d1; 1/d1 = R01*d0; same for (d2,d3).
  {
    const int g = tid >> 8, q = tid & 255;
    f2 acc0 = f2{0.f,0.f}, acc1 = f2{0.f,0.f}, acc2 = f2{0.f,0.f}, acc3 = f2{0.f,0.f};
    const f2 one2 = {1.f, 1.f};
    const float* xp = encE + (size_t)(b*DE + 64*g)*TE + 2*q;
    const float* ep = ebp + 64*g*8;
    const float* np = vnp + 64*g*2;
    #pragma unroll 2
    for (int i=0;i<64;i++){
      const f2 ea = *(const f2*)(xp + (size_t)i*TE);     // coalesced b64
      const float4 e01 = *(const float4*)(ep + i*8);     // uniform b128 {s0s0 s1s1}
      const float4 e23 = *(const float4*)(ep + i*8 + 4); // uniform b128 {s2s2 s3s3}
      const f2 vn2 = *(const f2*)(np + i*2);             // uniform b64
      const f2 d0 = pk_fma(ea, f2{e01.x, e01.y}, one2);
      const f2 d1 = pk_fma(ea, f2{e01.z, e01.w}, one2);
      const f2 d2 = pk_fma(ea, f2{e23.x, e23.y}, one2);
      const f2 d3 = pk_fma(ea, f2{e23.z, e23.w}, one2);
      const f2 D01 = pk_mul(d0, d1);                     // < 2^115.6 always
      const f2 D23 = pk_mul(d2, d3);
      const f2 R01 = {frcp(D01.x), frcp(D01.y)};
      const f2 R23 = {frcp(D23.x), frcp(D23.y)};
      acc0 = pk_fma(vn2, pk_mul(R01, d1), acc0);
      acc1 = pk_fma(vn2, pk_mul(R01, d0), acc1);
      acc2 = pk_fma(vn2, pk_mul(R23, d3), acc2);
      acc3 = pk_fma(vn2, pk_mul(R23, d2), acc3);
    }
    *(f2*)&part[(g*4 + 0)*TE + 2*q] = acc0;
    *(f2*)&part[(g*4 + 1)*TE + 2*q] = acc1;
    *(f2*)&part[(g*4 + 2)*TE + 2*q] = acc2;
    *(f2*)&part[(g*4 + 3)*TE + 2*q] = acc3;
  }
  __syncthreads();

  // ---- phase 2: wave w: s = w>>2, chunk c = w&3 (128 t). no max-subtract ----
  {
    const int w = tid >> 6, lane = tid & 63;
    const int s = w >> 2, c = w & 3;
    const int t0 = c*128 + 2*lane;
    f2 a = f2{0.f,0.f};
    #pragma unroll
    for (int g=0; g<4; g++){
      const f2 p = *(const f2*)&part[(g*4 + s)*TE + t0];
      a.x += p.x; a.y += p.y;
    }
    f2 ex; ex.x = fexp2(a.x); ex.y = fexp2(a.y);
    *(f2*)&part[(0*4 + s)*TE + t0] = ex;       // own slot (read above first)
    float sum = ex.x + ex.y;
    #pragma unroll
    for (int off=32; off>=1; off>>=1) sum += __shfl_xor(sum, off);
    if (lane==0) wsum[w] = sum;
    __syncthreads();
    const float S = wsum[s*4] + wsum[s*4+1] + wsum[s*4+2] + wsum[s*4+3];
    const float r = 1.0f / S;
    f2 wo; wo.x = ex.x*r; wo.y = ex.y*r;
    *(f2*)(outW + (size_t)(b*TD + s0 + s)*TE + t0) = wo;
    if (lane==0 && c==0) rs[s] = r;
  }
  // (no barrier needed: ex rows 0-3 published before the wsum barrier; ctx
  // partials go to rows 8-15, all phase-2 reads consumed before that barrier)

  // ---- phase 3: context. thread (h = t-quarter, e). 128 t x 4 s ----
  {
    const int h = tid >> 8, e = tid & 255;
    float c0=0.f, c1=0.f, c2=0.f, c3=0.f;
    const float* encB = enc + (size_t)(b*TE + 128*h)*DE + e;
    const int tb = 128*h;
    #pragma unroll 2
    for (int t4=0;t4<32;t4++){
      const float4 q0 = *(const float4*)&part[0*TE + tb + 4*t4];   // uniform b128
      const float4 q1 = *(const float4*)&part[1*TE + tb + 4*t4];
      const float4 q2 = *(const float4*)&part[2*TE + tb + 4*t4];
      const float4 q3 = *(const float4*)&part[3*TE + tb + 4*t4];
      const float f0 = encB[(size_t)(4*t4  )*DE];                  // coalesced
      const float f1 = encB[(size_t)(4*t4+1)*DE];
      const float f2_ = encB[(size_t)(4*t4+2)*DE];
      const float f3 = encB[(size_t)(4*t4+3)*DE];
      c0 += q0.x*f0+q0.y*f1+q0.z*f2_+q0.w*f3;
      c1 += q1.x*f0+q1.y*f1+q1.z*f2_+q1.w*f3;
      c2 += q2.x*f0+q2.y*f1+q2.z*f2_+q2.w*f3;
      c3 += q3.x*f0+q3.y*f1+q3.z*f2_+q3.w*f3;
    }
    float* partc = part + 8*TE;    // rows 8-15: [h*4+s][e]
    partc[(h*4+0)*DE + e] = c0;
    partc[(h*4+1)*DE + e] = c1;
    partc[(h*4+2)*DE + e] = c2;
    partc[(h*4+3)*DE + e] = c3;
  }
  __syncthreads();
  if (tid < DE){
    const float* partc = part + 8*TE;
    #pragma unroll
    for (int s=0;s<4;s++){
      const float val = (partc[(0*4+s)*DE + tid] + partc[(1*4+s)*DE + tid]
                       + partc[(2*4+s)*DE + tid] + partc[(3*4+s)*DE + tid]) * rs[s];
      outCtx[(size_t)(b*TD + s0 + s)*DE + tid] = val;
    }
  }
}

extern "C" void kernel_launch(void* const* d_in, const int* in_sizes, int n_in,
                              void* d_out, int out_size, void* d_ws, size_t ws_size,
                              hipStream_t stream)
{
  const float* enc  = (const float*)d_in[0];
  const float* dec  = (const float*)d_in[1];
  const float* Wenc = (const float*)d_in[2];
  const float* Wdec = (const float*)d_in[3];
  const float* v    = (const float*)d_in[4];
  float* outCtx = (float*)d_out;                       // (8,256,256)
  float* outW   = outCtx + (size_t)B*TD*DE;            // (8,256,512) = 4 MB
  float* encE   = (float*)d_ws;                        // 4 MB
  float* decP   = outW;                                // dec partial dots live
                                                       // in outW until attn
                                                       // overwrites with weights

  hipLaunchKernelGGL(prep_kernel, dim3(512), dim3(1024), 0, stream,
                     enc, Wenc, dec, Wdec, encE, decP);
  hipLaunchKernelGGL(attn_kernel, dim3(512), dim3(1024), 0, stream,
                     enc, v, encE, decP, outCtx, outW);
}